// Round 1
// baseline (3507.431 us; speedup 1.0000x reference)
//
#include <hip/hip_runtime.h>
#include <math.h>

#define DIM 256

typedef __bf16 bf16x8 __attribute__((ext_vector_type(8)));
typedef float f32x4 __attribute__((ext_vector_type(4)));

__device__ inline bf16x8 load8_bf16(const float* __restrict__ p) {
    const float4 a = *reinterpret_cast<const float4*>(p);
    const float4 b = *reinterpret_cast<const float4*>(p + 4);
    bf16x8 r;
    r[0] = (__bf16)a.x; r[1] = (__bf16)a.y; r[2] = (__bf16)a.z; r[3] = (__bf16)a.w;
    r[4] = (__bf16)b.x; r[5] = (__bf16)b.y; r[6] = (__bf16)b.z; r[7] = (__bf16)b.w;
    return r;
}

// H = relu(X @ W^T + bias)   X: (nrow,256) f32, W: (256,256) f32 row-major (out,k)
// Block: 256 thr = 4 waves. BM=64 rows, each wave owns 64 cols (BN=256 total).
__global__ __launch_bounds__(256) void gemm_relu_bt(
    const float* __restrict__ X, const float* __restrict__ W,
    const float* __restrict__ bias, float* __restrict__ H, int nrow)
{
    const int wv = threadIdx.x >> 6;
    const int lane = threadIdx.x & 63;
    const int lr = lane & 15;           // row/col within 16-tile
    const int lk = (lane >> 4) << 3;    // k offset within 32-step
    const int r0 = blockIdx.x << 6;
    const int cw = wv << 6;             // wave col base

    f32x4 acc[4][4] = {};
    int rowc[4];
#pragma unroll
    for (int mt = 0; mt < 4; ++mt) {
        int r = r0 + mt * 16 + lr;
        rowc[mt] = (r < nrow) ? r : (nrow - 1);
    }

    for (int kk = 0; kk < DIM; kk += 32) {
        bf16x8 af[4], bfr[4];
#pragma unroll
        for (int mt = 0; mt < 4; ++mt)
            af[mt] = load8_bf16(X + (size_t)rowc[mt] * DIM + kk + lk);
#pragma unroll
        for (int nt = 0; nt < 4; ++nt)
            bfr[nt] = load8_bf16(W + (size_t)(cw + nt * 16 + lr) * DIM + kk + lk);
#pragma unroll
        for (int mt = 0; mt < 4; ++mt)
#pragma unroll
            for (int nt = 0; nt < 4; ++nt)
                acc[mt][nt] = __builtin_amdgcn_mfma_f32_16x16x32_bf16(
                    af[mt], bfr[nt], acc[mt][nt], 0, 0, 0);
    }

    const int rbase = (lane >> 4) << 2;
    float bcol[4];
#pragma unroll
    for (int nt = 0; nt < 4; ++nt) bcol[nt] = bias[cw + nt * 16 + lr];
#pragma unroll
    for (int mt = 0; mt < 4; ++mt) {
#pragma unroll
        for (int r = 0; r < 4; ++r) {
            int row = r0 + mt * 16 + rbase + r;
            if (row >= nrow) continue;
#pragma unroll
            for (int nt = 0; nt < 4; ++nt) {
                int col = cw + nt * 16 + lr;
                float v = acc[mt][nt][r] + bcol[nt];
                H[(size_t)row * DIM + col] = fmaxf(v, 0.0f);
            }
        }
    }
}

// AGG[src] += H[tgt] * ew ; DEG[src] += 1.   One wave per edge.
__global__ __launch_bounds__(256) void scatter_add(
    const float* __restrict__ H, const int* __restrict__ esrc,
    const int* __restrict__ etgt, const float* __restrict__ ew,
    float* __restrict__ AGG, float* __restrict__ DEG, int E)
{
    int e = (blockIdx.x << 2) + (threadIdx.x >> 6);
    if (e >= E) return;
    int lane = threadIdx.x & 63;
    int s = esrc[e];
    int t = etgt[e];
    float w = ew[e];
    const float4 h4 = *reinterpret_cast<const float4*>(H + (size_t)t * DIM + (lane << 2));
    float* ap = AGG + (size_t)s * DIM + (lane << 2);
    atomicAdd(ap + 0, h4.x * w);
    atomicAdd(ap + 1, h4.y * w);
    atomicAdd(ap + 2, h4.z * w);
    atomicAdd(ap + 3, h4.w * w);
    if (lane == 0) atomicAdd(DEG + s, 1.0f);
}

// Per node: aggr = AGG/max(DEG,1); s = exp(leaky_relu(dot(aggr,u1)+dot(x_node,u2)));
// NUM (+)= s*aggr ; DEN (+)= s.  mode 0 = first relation (init + compute XU).
__global__ __launch_bounds__(256) void score_accum(
    const float* __restrict__ AGG, const float* __restrict__ DEG,
    const float* __restrict__ x_node, const float* __restrict__ u,
    float* __restrict__ NUM, float* __restrict__ DEN, float* __restrict__ XU,
    int nrow, int mode)
{
    int i = (blockIdx.x << 2) + (threadIdx.x >> 6);
    if (i >= nrow) return;
    int lane = threadIdx.x & 63;
    float deg = fmaxf(DEG[i], 1.0f);
    float inv = 1.0f / deg;
    float4 ag = *reinterpret_cast<const float4*>(AGG + (size_t)i * DIM + (lane << 2));
    ag.x *= inv; ag.y *= inv; ag.z *= inv; ag.w *= inv;

    float4 u1 = *reinterpret_cast<const float4*>(u + (lane << 2));
    float pa = ag.x * u1.x + ag.y * u1.y + ag.z * u1.z + ag.w * u1.w;
#pragma unroll
    for (int m = 1; m < 64; m <<= 1) pa += __shfl_xor(pa, m);

    float xu;
    if (mode == 0) {
        float4 xn = *reinterpret_cast<const float4*>(x_node + (size_t)i * DIM + (lane << 2));
        float4 u2 = *reinterpret_cast<const float4*>(u + DIM + (lane << 2));
        float p2 = xn.x * u2.x + xn.y * u2.y + xn.z * u2.z + xn.w * u2.w;
#pragma unroll
        for (int m = 1; m < 64; m <<= 1) p2 += __shfl_xor(p2, m);
        xu = p2;
        if (lane == 0) XU[i] = xu;
    } else {
        xu = XU[i];
    }

    float z = pa + xu;
    float lrv = (z > 0.0f) ? z : 0.01f * z;
    float s = expf(lrv);

    float* np = NUM + (size_t)i * DIM + (lane << 2);
    if (mode == 0) {
        float4 o;
        o.x = s * ag.x; o.y = s * ag.y; o.z = s * ag.z; o.w = s * ag.w;
        *reinterpret_cast<float4*>(np) = o;
        if (lane == 0) DEN[i] = s;
    } else {
        float4 o = *reinterpret_cast<float4*>(np);
        o.x += s * ag.x; o.y += s * ag.y; o.z += s * ag.z; o.w += s * ag.w;
        *reinterpret_cast<float4*>(np) = o;
        if (lane == 0) DEN[i] += s;
    }
}

// C = NUM / DEN (row-broadcast divide)
__global__ __launch_bounds__(256) void combine_div(
    const float* __restrict__ NUM, const float* __restrict__ DEN,
    float* __restrict__ C, int nrow)
{
    int total = nrow * (DIM / 4);
    for (int idx = blockIdx.x * blockDim.x + threadIdx.x; idx < total;
         idx += gridDim.x * blockDim.x) {
        int row = idx >> 6;  // 64 float4 per row
        float inv = 1.0f / DEN[row];
        float4 v = reinterpret_cast<const float4*>(NUM)[idx];
        v.x *= inv; v.y *= inv; v.z *= inv; v.w *= inv;
        reinterpret_cast<float4*>(C)[idx] = v;
    }
}

// OUT = rownorm(relu([x_node | CB] @ Wl^T + bl)).  Wl: (256,512) row-major.
__global__ __launch_bounds__(256) void gemm2_norm(
    const float* __restrict__ XN, const float* __restrict__ CB,
    const float* __restrict__ Wl, const float* __restrict__ bl,
    float* __restrict__ OUT, int nrow)
{
    const int wv = threadIdx.x >> 6;
    const int lane = threadIdx.x & 63;
    const int lr = lane & 15;
    const int lk = (lane >> 4) << 3;
    const int r0 = blockIdx.x << 6;
    const int cw = wv << 6;

    f32x4 acc[4][4] = {};
    int rowc[4];
#pragma unroll
    for (int mt = 0; mt < 4; ++mt) {
        int r = r0 + mt * 16 + lr;
        rowc[mt] = (r < nrow) ? r : (nrow - 1);
    }

    for (int kk = 0; kk < 2 * DIM; kk += 32) {
        const float* Abase = (kk < DIM) ? XN : CB;
        const int koff = (kk < DIM) ? kk : (kk - DIM);
        bf16x8 af[4], bfr[4];
#pragma unroll
        for (int mt = 0; mt < 4; ++mt)
            af[mt] = load8_bf16(Abase + (size_t)rowc[mt] * DIM + koff + lk);
#pragma unroll
        for (int nt = 0; nt < 4; ++nt)
            bfr[nt] = load8_bf16(Wl + (size_t)(cw + nt * 16 + lr) * (2 * DIM) + kk + lk);
#pragma unroll
        for (int mt = 0; mt < 4; ++mt)
#pragma unroll
            for (int nt = 0; nt < 4; ++nt)
                acc[mt][nt] = __builtin_amdgcn_mfma_f32_16x16x32_bf16(
                    af[mt], bfr[nt], acc[mt][nt], 0, 0, 0);
    }

    __shared__ float rs[4][64];
    const int rbase = (lane >> 4) << 2;
    float bcol[4];
#pragma unroll
    for (int nt = 0; nt < 4; ++nt) bcol[nt] = bl[cw + nt * 16 + lr];

    float ssq[4][4];
#pragma unroll
    for (int mt = 0; mt < 4; ++mt) {
#pragma unroll
        for (int r = 0; r < 4; ++r) {
            float ss = 0.0f;
#pragma unroll
            for (int nt = 0; nt < 4; ++nt) {
                float v = acc[mt][nt][r] + bcol[nt];
                v = fmaxf(v, 0.0f);
                acc[mt][nt][r] = v;
                ss += v * v;
            }
            ss += __shfl_xor(ss, 1);
            ss += __shfl_xor(ss, 2);
            ss += __shfl_xor(ss, 4);
            ss += __shfl_xor(ss, 8);
            ssq[mt][r] = ss;
        }
    }
    if (lr == 0) {
#pragma unroll
        for (int mt = 0; mt < 4; ++mt)
#pragma unroll
            for (int r = 0; r < 4; ++r)
                rs[wv][mt * 16 + rbase + r] = ssq[mt][r];
    }
    __syncthreads();

#pragma unroll
    for (int mt = 0; mt < 4; ++mt) {
#pragma unroll
        for (int r = 0; r < 4; ++r) {
            int rl = mt * 16 + rbase + r;
            int row = r0 + rl;
            if (row >= nrow) continue;
            float tot = rs[0][rl] + rs[1][rl] + rs[2][rl] + rs[3][rl];
            float nrm = fmaxf(sqrtf(tot), 1e-12f);
            float invn = 1.0f / nrm;
#pragma unroll
            for (int nt = 0; nt < 4; ++nt)
                OUT[(size_t)row * DIM + cw + nt * 16 + lr] = acc[mt][nt][r] * invn;
        }
    }
}

extern "C" void kernel_launch(void* const* d_in, const int* in_sizes, int n_in,
                              void* d_out, int out_size, void* d_ws, size_t ws_size,
                              hipStream_t stream)
{
    const float* x_a    = (const float*)d_in[0];
    const float* x_p    = (const float*)d_in[1];
    const float* x_v    = (const float*)d_in[2];
    const int*   edge_a = (const int*)d_in[3];
    const int*   edge_p = (const int*)d_in[4];
    const int*   edge_v = (const int*)d_in[5];
    const float* ew_a   = (const float*)d_in[6];
    const float* ew_p   = (const float*)d_in[7];
    const float* ew_v   = (const float*)d_in[8];
    const float* x_node = (const float*)d_in[9];
    // d_in[10] = num_node scalar (unused; derive from in_sizes)
    const float* W_a    = (const float*)d_in[11];
    const float* b_a    = (const float*)d_in[12];
    const float* W_p    = (const float*)d_in[13];
    const float* b_p    = (const float*)d_in[14];
    const float* W_v    = (const float*)d_in[15];
    const float* b_v    = (const float*)d_in[16];
    const float* u      = (const float*)d_in[17];
    const float* W_lin  = (const float*)d_in[18];
    const float* b_lin  = (const float*)d_in[19];
    float* out = (float*)d_out;

    const int N = in_sizes[0] / DIM;
    const int E = in_sizes[6];

    float* ws  = (float*)d_ws;
    float* H   = ws;                          // N*256  (h_r, later combined)
    float* AGG = H + (size_t)N * DIM;         // N*256  (per-relation aggregate)
    float* NUM = AGG + (size_t)N * DIM;       // N*256  (sum s_r * aggr_r)
    float* DEG = NUM + (size_t)N * DIM;       // N
    float* DEN = DEG + N;                     // N
    float* XU  = DEN + N;                     // N      (dot(x_node, u2) cache)

    const int gemm_grid = (N + 63) / 64;
    const int edge_grid = (E + 3) / 4;
    const int node_grid = (N + 3) / 4;

    const float* Xs[3]  = {x_a, x_p, x_v};
    const int*   Es[3]  = {edge_a, edge_p, edge_v};
    const float* EWs[3] = {ew_a, ew_p, ew_v};
    const float* Ws[3]  = {W_a, W_p, W_v};
    const float* Bs[3]  = {b_a, b_p, b_v};

    for (int r = 0; r < 3; ++r) {
        hipMemsetAsync(AGG, 0, (size_t)N * DIM * sizeof(float), stream);
        hipMemsetAsync(DEG, 0, (size_t)N * sizeof(float), stream);
        gemm_relu_bt<<<gemm_grid, 256, 0, stream>>>(Xs[r], Ws[r], Bs[r], H, N);
        scatter_add<<<edge_grid, 256, 0, stream>>>(H, Es[r], Es[r] + E, EWs[r], AGG, DEG, E);
        score_accum<<<node_grid, 256, 0, stream>>>(AGG, DEG, x_node, u, NUM, DEN, XU, N,
                                                   (r == 0) ? 0 : 1);
    }
    combine_div<<<1024, 256, 0, stream>>>(NUM, DEN, H, N);
    gemm2_norm<<<gemm_grid, 256, 0, stream>>>(x_node, H, W_lin, b_lin, out, N);
}

// Round 2
// 700.975 us; speedup vs baseline: 5.0036x; 5.0036x over previous
//
#include <hip/hip_runtime.h>
#include <math.h>

#define DIM 256

typedef __bf16 bf16x8 __attribute__((ext_vector_type(8)));
typedef float f32x4 __attribute__((ext_vector_type(4)));

__device__ inline bf16x8 load8_bf16(const float* __restrict__ p) {
    const float4 a = *reinterpret_cast<const float4*>(p);
    const float4 b = *reinterpret_cast<const float4*>(p + 4);
    bf16x8 r;
    r[0] = (__bf16)a.x; r[1] = (__bf16)a.y; r[2] = (__bf16)a.z; r[3] = (__bf16)a.w;
    r[4] = (__bf16)b.x; r[5] = (__bf16)b.y; r[6] = (__bf16)b.z; r[7] = (__bf16)b.w;
    return r;
}

// H = relu(X @ W^T + bias)   X: (nrow,256) f32, W: (256,256) f32 row-major (out,k)
__global__ __launch_bounds__(256) void gemm_relu_bt(
    const float* __restrict__ X, const float* __restrict__ W,
    const float* __restrict__ bias, float* __restrict__ H, int nrow)
{
    const int wv = threadIdx.x >> 6;
    const int lane = threadIdx.x & 63;
    const int lr = lane & 15;
    const int lk = (lane >> 4) << 3;
    const int r0 = blockIdx.x << 6;
    const int cw = wv << 6;

    f32x4 acc[4][4] = {};
    int rowc[4];
#pragma unroll
    for (int mt = 0; mt < 4; ++mt) {
        int r = r0 + mt * 16 + lr;
        rowc[mt] = (r < nrow) ? r : (nrow - 1);
    }

    for (int kk = 0; kk < DIM; kk += 32) {
        bf16x8 af[4], bfr[4];
#pragma unroll
        for (int mt = 0; mt < 4; ++mt)
            af[mt] = load8_bf16(X + (size_t)rowc[mt] * DIM + kk + lk);
#pragma unroll
        for (int nt = 0; nt < 4; ++nt)
            bfr[nt] = load8_bf16(W + (size_t)(cw + nt * 16 + lr) * DIM + kk + lk);
#pragma unroll
        for (int mt = 0; mt < 4; ++mt)
#pragma unroll
            for (int nt = 0; nt < 4; ++nt)
                acc[mt][nt] = __builtin_amdgcn_mfma_f32_16x16x32_bf16(
                    af[mt], bfr[nt], acc[mt][nt], 0, 0, 0);
    }

    const int rbase = (lane >> 4) << 2;
    float bcol[4];
#pragma unroll
    for (int nt = 0; nt < 4; ++nt) bcol[nt] = bias[cw + nt * 16 + lr];
#pragma unroll
    for (int mt = 0; mt < 4; ++mt) {
#pragma unroll
        for (int r = 0; r < 4; ++r) {
            int row = r0 + mt * 16 + rbase + r;
            if (row >= nrow) continue;
#pragma unroll
            for (int nt = 0; nt < 4; ++nt) {
                int col = cw + nt * 16 + lr;
                float v = acc[mt][nt][r] + bcol[nt];
                H[(size_t)row * DIM + col] = fmaxf(v, 0.0f);
            }
        }
    }
}

// cnt[src[e]] += 1
__global__ __launch_bounds__(256) void hist_src(
    const int* __restrict__ esrc, int* __restrict__ cnt, int E)
{
    int e = blockIdx.x * 256 + threadIdx.x;
    if (e < E) atomicAdd(&cnt[esrc[e]], 1);
}

// Assign each node a contiguous segment [start[i], start[i]+cnt[i]).
// Wave-level exclusive scan + one global atomic per wave. Order of segments
// across waves is arbitrary -- only grouping matters. cursor := start.
__global__ __launch_bounds__(256) void seg_assign(
    const int* __restrict__ cnt, int* __restrict__ start,
    int* __restrict__ cursor, int* __restrict__ total, int N)
{
    int i = blockIdx.x * 256 + threadIdx.x;
    int lane = threadIdx.x & 63;
    int c = (i < N) ? cnt[i] : 0;
    int p = c;
#pragma unroll
    for (int m = 1; m < 64; m <<= 1) {
        int t = __shfl_up(p, m);
        if (lane >= m) p += t;
    }
    int wsum = __shfl(p, 63);
    int base = 0;
    if (lane == 63) base = atomicAdd(total, wsum);
    base = __shfl(base, 63);
    if (i < N) {
        int st = base + p - c;
        start[i] = st;
        cursor[i] = st;
    }
}

// Scatter edge (tgt, w) into its src's segment.
__global__ __launch_bounds__(256) void fill_csr(
    const int* __restrict__ esrc, const int* __restrict__ etgt,
    const float* __restrict__ ew, int* __restrict__ cursor,
    int* __restrict__ tgt_s, float* __restrict__ w_s, int E)
{
    int e = blockIdx.x * 256 + threadIdx.x;
    if (e >= E) return;
    int s = esrc[e];
    int pos = atomicAdd(&cursor[s], 1);
    tgt_s[pos] = etgt[e];
    w_s[pos] = ew[e];
}

// Per node (one wave): aggr = (sum_j w_j * H[tgt_j]) / max(deg,1);
// s = exp(leaky_relu(dot(aggr,u1) + xu)); NUM (+)= s*aggr; DEN (+)= s.
__global__ __launch_bounds__(256) void gather_score(
    const float* __restrict__ H, const int* __restrict__ start,
    const int* __restrict__ cnt, const int* __restrict__ tgt_s,
    const float* __restrict__ w_s, const float* __restrict__ x_node,
    const float* __restrict__ u, float* __restrict__ NUM,
    float* __restrict__ DEN, float* __restrict__ XU, int nrow, int mode)
{
    int i = (blockIdx.x << 2) + (threadIdx.x >> 6);
    if (i >= nrow) return;
    int lane = threadIdx.x & 63;
    int s0 = start[i];
    int c = cnt[i];

    float4 ag = {0.f, 0.f, 0.f, 0.f};
    for (int j = 0; j < c; ++j) {
        int t = tgt_s[s0 + j];
        float w = w_s[s0 + j];
        const float4 h4 = *reinterpret_cast<const float4*>(H + (size_t)t * DIM + (lane << 2));
        ag.x += h4.x * w; ag.y += h4.y * w; ag.z += h4.z * w; ag.w += h4.w * w;
    }
    float inv = 1.0f / fmaxf((float)c, 1.0f);
    ag.x *= inv; ag.y *= inv; ag.z *= inv; ag.w *= inv;

    float4 u1 = *reinterpret_cast<const float4*>(u + (lane << 2));
    float pa = ag.x * u1.x + ag.y * u1.y + ag.z * u1.z + ag.w * u1.w;
#pragma unroll
    for (int m = 1; m < 64; m <<= 1) pa += __shfl_xor(pa, m);

    float xu;
    if (mode == 0) {
        float4 xn = *reinterpret_cast<const float4*>(x_node + (size_t)i * DIM + (lane << 2));
        float4 u2 = *reinterpret_cast<const float4*>(u + DIM + (lane << 2));
        float p2 = xn.x * u2.x + xn.y * u2.y + xn.z * u2.z + xn.w * u2.w;
#pragma unroll
        for (int m = 1; m < 64; m <<= 1) p2 += __shfl_xor(p2, m);
        xu = p2;
        if (lane == 0) XU[i] = xu;
    } else {
        xu = XU[i];
    }

    float z = pa + xu;
    float lrv = (z > 0.0f) ? z : 0.01f * z;
    float s = expf(lrv);

    float* np = NUM + (size_t)i * DIM + (lane << 2);
    if (mode == 0) {
        float4 o;
        o.x = s * ag.x; o.y = s * ag.y; o.z = s * ag.z; o.w = s * ag.w;
        *reinterpret_cast<float4*>(np) = o;
        if (lane == 0) DEN[i] = s;
    } else {
        float4 o = *reinterpret_cast<float4*>(np);
        o.x += s * ag.x; o.y += s * ag.y; o.z += s * ag.z; o.w += s * ag.w;
        *reinterpret_cast<float4*>(np) = o;
        if (lane == 0) DEN[i] += s;
    }
}

// C = NUM / DEN (row-broadcast divide)
__global__ __launch_bounds__(256) void combine_div(
    const float* __restrict__ NUM, const float* __restrict__ DEN,
    float* __restrict__ C, int nrow)
{
    int total = nrow * (DIM / 4);
    for (int idx = blockIdx.x * blockDim.x + threadIdx.x; idx < total;
         idx += gridDim.x * blockDim.x) {
        int row = idx >> 6;
        float inv = 1.0f / DEN[row];
        float4 v = reinterpret_cast<const float4*>(NUM)[idx];
        v.x *= inv; v.y *= inv; v.z *= inv; v.w *= inv;
        reinterpret_cast<float4*>(C)[idx] = v;
    }
}

// OUT = rownorm(relu([x_node | CB] @ Wl^T + bl)).  Wl: (256,512) row-major.
__global__ __launch_bounds__(256) void gemm2_norm(
    const float* __restrict__ XN, const float* __restrict__ CB,
    const float* __restrict__ Wl, const float* __restrict__ bl,
    float* __restrict__ OUT, int nrow)
{
    const int wv = threadIdx.x >> 6;
    const int lane = threadIdx.x & 63;
    const int lr = lane & 15;
    const int lk = (lane >> 4) << 3;
    const int r0 = blockIdx.x << 6;
    const int cw = wv << 6;

    f32x4 acc[4][4] = {};
    int rowc[4];
#pragma unroll
    for (int mt = 0; mt < 4; ++mt) {
        int r = r0 + mt * 16 + lr;
        rowc[mt] = (r < nrow) ? r : (nrow - 1);
    }

    for (int kk = 0; kk < 2 * DIM; kk += 32) {
        const float* Abase = (kk < DIM) ? XN : CB;
        const int koff = (kk < DIM) ? kk : (kk - DIM);
        bf16x8 af[4], bfr[4];
#pragma unroll
        for (int mt = 0; mt < 4; ++mt)
            af[mt] = load8_bf16(Abase + (size_t)rowc[mt] * DIM + koff + lk);
#pragma unroll
        for (int nt = 0; nt < 4; ++nt)
            bfr[nt] = load8_bf16(Wl + (size_t)(cw + nt * 16 + lr) * (2 * DIM) + kk + lk);
#pragma unroll
        for (int mt = 0; mt < 4; ++mt)
#pragma unroll
            for (int nt = 0; nt < 4; ++nt)
                acc[mt][nt] = __builtin_amdgcn_mfma_f32_16x16x32_bf16(
                    af[mt], bfr[nt], acc[mt][nt], 0, 0, 0);
    }

    __shared__ float rs[4][64];
    const int rbase = (lane >> 4) << 2;
    float bcol[4];
#pragma unroll
    for (int nt = 0; nt < 4; ++nt) bcol[nt] = bl[cw + nt * 16 + lr];

    float ssq[4][4];
#pragma unroll
    for (int mt = 0; mt < 4; ++mt) {
#pragma unroll
        for (int r = 0; r < 4; ++r) {
            float ss = 0.0f;
#pragma unroll
            for (int nt = 0; nt < 4; ++nt) {
                float v = acc[mt][nt][r] + bcol[nt];
                v = fmaxf(v, 0.0f);
                acc[mt][nt][r] = v;
                ss += v * v;
            }
            ss += __shfl_xor(ss, 1);
            ss += __shfl_xor(ss, 2);
            ss += __shfl_xor(ss, 4);
            ss += __shfl_xor(ss, 8);
            ssq[mt][r] = ss;
        }
    }
    if (lr == 0) {
#pragma unroll
        for (int mt = 0; mt < 4; ++mt)
#pragma unroll
            for (int r = 0; r < 4; ++r)
                rs[wv][mt * 16 + rbase + r] = ssq[mt][r];
    }
    __syncthreads();

#pragma unroll
    for (int mt = 0; mt < 4; ++mt) {
#pragma unroll
        for (int r = 0; r < 4; ++r) {
            int rl = mt * 16 + rbase + r;
            int row = r0 + rl;
            if (row >= nrow) continue;
            float tot = rs[0][rl] + rs[1][rl] + rs[2][rl] + rs[3][rl];
            float nrm = fmaxf(sqrtf(tot), 1e-12f);
            float invn = 1.0f / nrm;
#pragma unroll
            for (int nt = 0; nt < 4; ++nt)
                OUT[(size_t)row * DIM + cw + nt * 16 + lr] = acc[mt][nt][r] * invn;
        }
    }
}

extern "C" void kernel_launch(void* const* d_in, const int* in_sizes, int n_in,
                              void* d_out, int out_size, void* d_ws, size_t ws_size,
                              hipStream_t stream)
{
    const float* x_a    = (const float*)d_in[0];
    const float* x_p    = (const float*)d_in[1];
    const float* x_v    = (const float*)d_in[2];
    const int*   edge_a = (const int*)d_in[3];
    const int*   edge_p = (const int*)d_in[4];
    const int*   edge_v = (const int*)d_in[5];
    const float* ew_a   = (const float*)d_in[6];
    const float* ew_p   = (const float*)d_in[7];
    const float* ew_v   = (const float*)d_in[8];
    const float* x_node = (const float*)d_in[9];
    const float* W_a    = (const float*)d_in[11];
    const float* b_a    = (const float*)d_in[12];
    const float* W_p    = (const float*)d_in[13];
    const float* b_p    = (const float*)d_in[14];
    const float* W_v    = (const float*)d_in[15];
    const float* b_v    = (const float*)d_in[16];
    const float* u      = (const float*)d_in[17];
    const float* W_lin  = (const float*)d_in[18];
    const float* b_lin  = (const float*)d_in[19];
    float* out = (float*)d_out;

    const int N = in_sizes[0] / DIM;
    const int E = in_sizes[6];

    float* ws  = (float*)d_ws;
    float* H     = ws;                           // N*256
    float* NUM   = H + (size_t)N * DIM;          // N*256
    float* w_s   = NUM + (size_t)N * DIM;        // E
    int*   tgt_s = (int*)(w_s + E);              // E
    int*   cnt   = tgt_s + E;                    // N
    int*   start = cnt + N;                      // N
    int*   cursor= start + N;                    // N
    int*   total = cursor + N;                   // 1
    float* DEN   = (float*)(total + 1);          // N
    float* XU    = DEN + N;                      // N

    const int gemm_grid = (N + 63) / 64;
    const int node_grid = (N + 3) / 4;
    const int egrid     = (E + 255) / 256;
    const int ngrid     = (N + 255) / 256;

    const float* Xs[3]  = {x_a, x_p, x_v};
    const int*   Es[3]  = {edge_a, edge_p, edge_v};
    const float* EWs[3] = {ew_a, ew_p, ew_v};
    const float* Ws[3]  = {W_a, W_p, W_v};
    const float* Bs[3]  = {b_a, b_p, b_v};

    for (int r = 0; r < 3; ++r) {
        hipMemsetAsync(cnt, 0, (size_t)N * sizeof(int), stream);
        hipMemsetAsync(total, 0, sizeof(int), stream);
        gemm_relu_bt<<<gemm_grid, 256, 0, stream>>>(Xs[r], Ws[r], Bs[r], H, N);
        hist_src<<<egrid, 256, 0, stream>>>(Es[r], cnt, E);
        seg_assign<<<ngrid, 256, 0, stream>>>(cnt, start, cursor, total, N);
        fill_csr<<<egrid, 256, 0, stream>>>(Es[r], Es[r] + E, EWs[r], cursor, tgt_s, w_s, E);
        gather_score<<<node_grid, 256, 0, stream>>>(H, start, cnt, tgt_s, w_s, x_node, u,
                                                    NUM, DEN, XU, N, (r == 0) ? 0 : 1);
    }
    combine_div<<<1024, 256, 0, stream>>>(NUM, DEN, H, N);
    gemm2_norm<<<gemm_grid, 256, 0, stream>>>(x_node, H, W_lin, b_lin, out, N);
}

// Round 3
// 370.030 us; speedup vs baseline: 9.4788x; 1.8944x over previous
//
#include <hip/hip_runtime.h>
#include <math.h>

#define DIM 256

typedef __bf16 bf16x8 __attribute__((ext_vector_type(8)));
typedef __bf16 bf16x4 __attribute__((ext_vector_type(4)));
typedef float f32x4 __attribute__((ext_vector_type(4)));

#define GLOBAL_AS(p) ((const __attribute__((address_space(1))) void*)(p))
#define LDS_AS(p)    ((__attribute__((address_space(3))) void*)(p))

// ---------------------------------------------------------------------------
// Fused GEMM: OUT = epilogue(A @ B^T + bias)
//   A: (nrow, KDIM) logical; physically A0 f32 (cols 0..255) and (KDIM=512)
//      A1 bf16 (cols 256..511).  B: (256, KDIM) bf16 row-major.
//   MODE 0: relu -> OUTB bf16 (H for gather)
//   MODE 1: relu + row L2-normalize -> OUTF f32 (final output)
// Tile: BM=128 x BN=256, BK=32, 8 waves (2 row x 4 col), dbuf LDS.
// A is reg-staged (fuses f32->bf16 cvt), B via global_load_lds width=16.
// ---------------------------------------------------------------------------
template<int KDIM, int MODE>
__global__ __launch_bounds__(512) void gemm_fused(
    const float* __restrict__ A0, const __bf16* __restrict__ A1,
    const __bf16* __restrict__ B, const float* __restrict__ bias,
    float* __restrict__ OUTF, __bf16* __restrict__ OUTB, int nrow)
{
    __shared__ __bf16 As[2][128 * 32];
    __shared__ __bf16 Bs[2][256 * 32];
    __shared__ float rs[4][128];

    const int tid = threadIdx.x;
    const int w = tid >> 6, lane = tid & 63;
    const int wr = w >> 2, wc = w & 3;
    const int lr = lane & 15, lk = (lane >> 4) << 3;
    const int r0 = blockIdx.x << 7;

    // A staging coords: each thread stages 8 bf16 (16B) per K-step
    const int srow = tid >> 2;              // 0..127
    const int scb  = (tid & 3) << 3;        // 0,8,16,24 (elem offset in BK)
    const int arow_g = min(r0 + srow, nrow - 1);
    // B staging coords (global_load_lds, wave-uniform LDS base + lane*16B)
    const int brow0 = (w << 4) + (lane >> 2);   // 0..127 wave-linear
    const int bcol  = (lane & 3) << 3;

    const int KT = KDIM / 32;
    f32x4 acc[4][4] = {};

    // ---- prologue: stage kt=0 into buf 0 (kk=0 is always the f32 path)
    {
        const float* p = A0 + (size_t)arow_g * DIM + scb;
        float4 f0 = *reinterpret_cast<const float4*>(p);
        float4 f1 = *reinterpret_cast<const float4*>(p + 4);
        bf16x8 av;
        av[0] = (__bf16)f0.x; av[1] = (__bf16)f0.y; av[2] = (__bf16)f0.z; av[3] = (__bf16)f0.w;
        av[4] = (__bf16)f1.x; av[5] = (__bf16)f1.y; av[6] = (__bf16)f1.z; av[7] = (__bf16)f1.w;
        *reinterpret_cast<bf16x8*>(&As[0][srow * 32 + scb]) = av;
        __builtin_amdgcn_global_load_lds(
            GLOBAL_AS(B + (size_t)brow0 * KDIM + bcol),
            LDS_AS(&Bs[0][(w << 4) * 32]), 16, 0, 0);
        __builtin_amdgcn_global_load_lds(
            GLOBAL_AS(B + (size_t)(brow0 + 128) * KDIM + bcol),
            LDS_AS(&Bs[0][(128 + (w << 4)) * 32]), 16, 0, 0);
    }
    __syncthreads();

    int buf = 0;
    for (int kt = 0; kt < KT; ++kt) {
        const bool has_next = (kt + 1 < KT);
        bf16x8 av;
        if (has_next) {
            const int kn = (kt + 1) << 5;
            // prefetch next B tile (async -> LDS)
            __builtin_amdgcn_global_load_lds(
                GLOBAL_AS(B + (size_t)brow0 * KDIM + kn + bcol),
                LDS_AS(&Bs[buf ^ 1][(w << 4) * 32]), 16, 0, 0);
            __builtin_amdgcn_global_load_lds(
                GLOBAL_AS(B + (size_t)(brow0 + 128) * KDIM + kn + bcol),
                LDS_AS(&Bs[buf ^ 1][(128 + (w << 4)) * 32]), 16, 0, 0);
            // next A into regs (latency hides under MFMA below)
            if (KDIM == 512 && kn >= DIM) {
                av = *reinterpret_cast<const bf16x8*>(
                    A1 + (size_t)arow_g * DIM + (kn - DIM) + scb);
            } else {
                const float* p = A0 + (size_t)arow_g * DIM + kn + scb;
                float4 f0 = *reinterpret_cast<const float4*>(p);
                float4 f1 = *reinterpret_cast<const float4*>(p + 4);
                av[0] = (__bf16)f0.x; av[1] = (__bf16)f0.y; av[2] = (__bf16)f0.z; av[3] = (__bf16)f0.w;
                av[4] = (__bf16)f1.x; av[5] = (__bf16)f1.y; av[6] = (__bf16)f1.z; av[7] = (__bf16)f1.w;
            }
        }

        bf16x8 afr[4], bfr[4];
#pragma unroll
        for (int mt = 0; mt < 4; ++mt)
            afr[mt] = *reinterpret_cast<const bf16x8*>(
                &As[buf][((wr << 6) + (mt << 4) + lr) * 32 + lk]);
#pragma unroll
        for (int nt = 0; nt < 4; ++nt)
            bfr[nt] = *reinterpret_cast<const bf16x8*>(
                &Bs[buf][((wc << 6) + (nt << 4) + lr) * 32 + lk]);
#pragma unroll
        for (int mt = 0; mt < 4; ++mt)
#pragma unroll
            for (int nt = 0; nt < 4; ++nt)
                acc[mt][nt] = __builtin_amdgcn_mfma_f32_16x16x32_bf16(
                    afr[mt], bfr[nt], acc[mt][nt], 0, 0, 0);

        if (has_next)
            *reinterpret_cast<bf16x8*>(&As[buf ^ 1][srow * 32 + scb]) = av;
        __syncthreads();
        buf ^= 1;
    }

    const int rbase = (lane >> 4) << 2;
    float bcolv[4];
#pragma unroll
    for (int nt = 0; nt < 4; ++nt) bcolv[nt] = bias[(wc << 6) + (nt << 4) + lr];

    if (MODE == 0) {
#pragma unroll
        for (int mt = 0; mt < 4; ++mt)
#pragma unroll
            for (int r = 0; r < 4; ++r) {
                int row = r0 + (wr << 6) + (mt << 4) + rbase + r;
                if (row >= nrow) continue;
#pragma unroll
                for (int nt = 0; nt < 4; ++nt) {
                    float v = fmaxf(acc[mt][nt][r] + bcolv[nt], 0.0f);
                    OUTB[(size_t)row * DIM + (wc << 6) + (nt << 4) + lr] = (__bf16)v;
                }
            }
    } else {
        float ssq[4][4];
#pragma unroll
        for (int mt = 0; mt < 4; ++mt)
#pragma unroll
            for (int r = 0; r < 4; ++r) {
                float ss = 0.0f;
#pragma unroll
                for (int nt = 0; nt < 4; ++nt) {
                    float v = fmaxf(acc[mt][nt][r] + bcolv[nt], 0.0f);
                    acc[mt][nt][r] = v;
                    ss += v * v;
                }
                ss += __shfl_xor(ss, 1);
                ss += __shfl_xor(ss, 2);
                ss += __shfl_xor(ss, 4);
                ss += __shfl_xor(ss, 8);
                ssq[mt][r] = ss;
            }
        if (lr == 0) {
#pragma unroll
            for (int mt = 0; mt < 4; ++mt)
#pragma unroll
                for (int r = 0; r < 4; ++r)
                    rs[wc][(wr << 6) + (mt << 4) + rbase + r] = ssq[mt][r];
        }
        __syncthreads();
#pragma unroll
        for (int mt = 0; mt < 4; ++mt)
#pragma unroll
            for (int r = 0; r < 4; ++r) {
                int rl = (wr << 6) + (mt << 4) + rbase + r;
                int row = r0 + rl;
                if (row >= nrow) continue;
                float tot = rs[0][rl] + rs[1][rl] + rs[2][rl] + rs[3][rl];
                float invn = 1.0f / fmaxf(sqrtf(tot), 1e-12f);
#pragma unroll
                for (int nt = 0; nt < 4; ++nt)
                    OUTF[(size_t)row * DIM + (wc << 6) + (nt << 4) + lr] =
                        acc[mt][nt][r] * invn;
            }
    }
}

// ---------------------------------------------------------------------------
__global__ __launch_bounds__(256) void f32_to_bf16(
    const float* __restrict__ s, __bf16* __restrict__ d, int n)
{
    int i = blockIdx.x * 256 + threadIdx.x;
    if (i < n) d[i] = (__bf16)s[i];
}

// cnt3[r][src_r[e]] += 1 for all three relations
__global__ __launch_bounds__(256) void hist3(
    const int* __restrict__ ea, const int* __restrict__ ep,
    const int* __restrict__ ev, int* __restrict__ cnt3, int E, int N)
{
    int e = blockIdx.x * 256 + threadIdx.x;
    if (e >= E) return;
    atomicAdd(&cnt3[ea[e]], 1);
    atomicAdd(&cnt3[N + ep[e]], 1);
    atomicAdd(&cnt3[2 * N + ev[e]], 1);
}

// segment arena assignment over all 3N counters (wave scan + 1 atomic/wave)
__global__ __launch_bounds__(256) void seg3(
    const int* __restrict__ cnt3, int* __restrict__ start3,
    int* __restrict__ cursor3, int* __restrict__ total, int n3)
{
    int i = blockIdx.x * 256 + threadIdx.x;
    int lane = threadIdx.x & 63;
    int c = (i < n3) ? cnt3[i] : 0;
    int p = c;
#pragma unroll
    for (int m = 1; m < 64; m <<= 1) {
        int t = __shfl_up(p, m);
        if (lane >= m) p += t;
    }
    int wsum = __shfl(p, 63);
    int base = 0;
    if (lane == 63) base = atomicAdd(total, wsum);
    base = __shfl(base, 63);
    if (i < n3) {
        int st = base + p - c;
        start3[i] = st;
        cursor3[i] = st;
    }
}

__global__ __launch_bounds__(256) void fill3(
    const int* __restrict__ ea, const int* __restrict__ ep,
    const int* __restrict__ ev, const float* __restrict__ wa,
    const float* __restrict__ wp, const float* __restrict__ wv,
    int* __restrict__ cursor3, int* __restrict__ tgt_s,
    float* __restrict__ w_s, int E, int N)
{
    int e = blockIdx.x * 256 + threadIdx.x;
    if (e >= E) return;
    int s, pos;
    s = ea[e]; pos = atomicAdd(&cursor3[s], 1);         tgt_s[pos] = ea[E + e]; w_s[pos] = wa[e];
    s = ep[e]; pos = atomicAdd(&cursor3[N + s], 1);     tgt_s[pos] = ep[E + e]; w_s[pos] = wp[e];
    s = ev[e]; pos = atomicAdd(&cursor3[2 * N + s], 1); tgt_s[pos] = ev[E + e]; w_s[pos] = wv[e];
}

// Per node (1 wave): for each relation gather mean of w*H_r rows, score,
// softmax-combine across relations, write C row as bf16.
__global__ __launch_bounds__(256) void gather3(
    const __bf16* __restrict__ H3, const int* __restrict__ start3,
    const int* __restrict__ cnt3, const int* __restrict__ tgt_s,
    const float* __restrict__ w_s, const float* __restrict__ x_node,
    const float* __restrict__ u, __bf16* __restrict__ CB, int N)
{
    int i = (blockIdx.x << 2) + (threadIdx.x >> 6);
    if (i >= N) return;
    int lane = threadIdx.x & 63;

    float4 u1 = *reinterpret_cast<const float4*>(u + (lane << 2));
    float4 u2 = *reinterpret_cast<const float4*>(u + DIM + (lane << 2));
    float4 xn = *reinterpret_cast<const float4*>(x_node + (size_t)i * DIM + (lane << 2));
    float xu = xn.x * u2.x + xn.y * u2.y + xn.z * u2.z + xn.w * u2.w;
#pragma unroll
    for (int m = 1; m < 64; m <<= 1) xu += __shfl_xor(xu, m);

    float ags[3][4];
    float sc[3];
#pragma unroll 1
    for (int r = 0; r < 3; ++r) {
        int base = r * N + i;
        int s0 = start3[base];
        int c = cnt3[base];
        const __bf16* H = H3 + (size_t)r * N * DIM;
        float a0 = 0.f, a1 = 0.f, a2 = 0.f, a3 = 0.f;
        for (int j = 0; j < c; ++j) {
            int t = tgt_s[s0 + j];
            float wgt = w_s[s0 + j];
            bf16x4 h = *reinterpret_cast<const bf16x4*>(H + (size_t)t * DIM + (lane << 2));
            a0 += (float)h[0] * wgt;
            a1 += (float)h[1] * wgt;
            a2 += (float)h[2] * wgt;
            a3 += (float)h[3] * wgt;
        }
        float inv = 1.0f / fmaxf((float)c, 1.0f);
        a0 *= inv; a1 *= inv; a2 *= inv; a3 *= inv;
        ags[r][0] = a0; ags[r][1] = a1; ags[r][2] = a2; ags[r][3] = a3;
        float pa = a0 * u1.x + a1 * u1.y + a2 * u1.z + a3 * u1.w;
#pragma unroll
        for (int m = 1; m < 64; m <<= 1) pa += __shfl_xor(pa, m);
        float z = pa + xu;
        float lrv = (z > 0.0f) ? z : 0.01f * z;
        sc[r] = expf(lrv);
    }

    float invden = 1.0f / (sc[0] + sc[1] + sc[2]);
    float o0 = (sc[0] * ags[0][0] + sc[1] * ags[1][0] + sc[2] * ags[2][0]) * invden;
    float o1 = (sc[0] * ags[0][1] + sc[1] * ags[1][1] + sc[2] * ags[2][1]) * invden;
    float o2 = (sc[0] * ags[0][2] + sc[1] * ags[1][2] + sc[2] * ags[2][2]) * invden;
    float o3 = (sc[0] * ags[0][3] + sc[1] * ags[1][3] + sc[2] * ags[2][3]) * invden;
    bf16x4 ob;
    ob[0] = (__bf16)o0; ob[1] = (__bf16)o1; ob[2] = (__bf16)o2; ob[3] = (__bf16)o3;
    *reinterpret_cast<bf16x4*>(CB + (size_t)i * DIM + (lane << 2)) = ob;
}

// ---------------------------------------------------------------------------
extern "C" void kernel_launch(void* const* d_in, const int* in_sizes, int n_in,
                              void* d_out, int out_size, void* d_ws, size_t ws_size,
                              hipStream_t stream)
{
    const float* x_a    = (const float*)d_in[0];
    const float* x_p    = (const float*)d_in[1];
    const float* x_v    = (const float*)d_in[2];
    const int*   edge_a = (const int*)d_in[3];
    const int*   edge_p = (const int*)d_in[4];
    const int*   edge_v = (const int*)d_in[5];
    const float* ew_a   = (const float*)d_in[6];
    const float* ew_p   = (const float*)d_in[7];
    const float* ew_v   = (const float*)d_in[8];
    const float* x_node = (const float*)d_in[9];
    const float* W_a    = (const float*)d_in[11];
    const float* b_a    = (const float*)d_in[12];
    const float* W_p    = (const float*)d_in[13];
    const float* b_p    = (const float*)d_in[14];
    const float* W_v    = (const float*)d_in[15];
    const float* b_v    = (const float*)d_in[16];
    const float* u      = (const float*)d_in[17];
    const float* W_lin  = (const float*)d_in[18];
    const float* b_lin  = (const float*)d_in[19];
    float* out = (float*)d_out;

    const int N = in_sizes[0] / DIM;
    const int E = in_sizes[6];

    // workspace layout (16B-aligned sections)
    __bf16* H3   = (__bf16*)d_ws;                       // 3*N*256 bf16
    __bf16* CB   = H3 + (size_t)3 * N * DIM;            // N*256 bf16
    __bf16* WB   = CB + (size_t)N * DIM;                // 3*65536 bf16
    __bf16* WLB  = WB + 3 * 65536;                      // 131072 bf16
    float*  w_s  = (float*)(WLB + 131072);              // 3E f32 (arena)
    int*    tgt_s = (int*)(w_s + (size_t)3 * E);        // 3E int (arena)
    int*    cnt3 = tgt_s + (size_t)3 * E;               // 3N
    int*    start3 = cnt3 + 3 * N;                      // 3N
    int*    cursor3 = start3 + 3 * N;                   // 3N
    int*    total = cursor3 + 3 * N;                    // 1

    const int gemm_grid = (N + 127) / 128;
    const int egrid = (E + 255) / 256;

    // weight conversions (tiny)
    f32_to_bf16<<<(65536 + 255) / 256, 256, 0, stream>>>(W_a, WB, 65536);
    f32_to_bf16<<<(65536 + 255) / 256, 256, 0, stream>>>(W_p, WB + 65536, 65536);
    f32_to_bf16<<<(65536 + 255) / 256, 256, 0, stream>>>(W_v, WB + 2 * 65536, 65536);
    f32_to_bf16<<<(131072 + 255) / 256, 256, 0, stream>>>(W_lin, WLB, 131072);

    // CSR build (all 3 relations fused)
    hipMemsetAsync(cnt3, 0, (size_t)3 * N * sizeof(int), stream);
    hipMemsetAsync(total, 0, sizeof(int), stream);
    hist3<<<egrid, 256, 0, stream>>>(edge_a, edge_p, edge_v, cnt3, E, N);
    seg3<<<(3 * N + 255) / 256, 256, 0, stream>>>(cnt3, start3, cursor3, total, 3 * N);
    fill3<<<egrid, 256, 0, stream>>>(edge_a, edge_p, edge_v, ew_a, ew_p, ew_v,
                                     cursor3, tgt_s, w_s, E, N);

    // H_r = relu(X_r @ W_r^T + b_r)  (bf16 out)
    gemm_fused<256, 0><<<gemm_grid, 512, 0, stream>>>(
        x_a, (const __bf16*)nullptr, WB, b_a, (float*)nullptr, H3, N);
    gemm_fused<256, 0><<<gemm_grid, 512, 0, stream>>>(
        x_p, (const __bf16*)nullptr, WB + 65536, b_p, (float*)nullptr, H3 + (size_t)N * DIM, N);
    gemm_fused<256, 0><<<gemm_grid, 512, 0, stream>>>(
        x_v, (const __bf16*)nullptr, WB + 2 * 65536, b_v, (float*)nullptr, H3 + (size_t)2 * N * DIM, N);

    // fused gather + score + softmax-combine -> CB bf16
    gather3<<<(N + 3) / 4, 256, 0, stream>>>(H3, start3, cnt3, tgt_s, w_s,
                                             x_node, u, CB, N);

    // out = rownorm(relu([x_node | CB] @ W_lin^T + b_lin))
    gemm_fused<512, 1><<<gemm_grid, 512, 0, stream>>>(
        x_node, CB, WLB, b_lin, out, (__bf16*)nullptr, N);
}

// Round 4
// 340.143 us; speedup vs baseline: 10.3116x; 1.0879x over previous
//
#include <hip/hip_runtime.h>
#include <math.h>

#define DIM 256

typedef __bf16 bf16x8 __attribute__((ext_vector_type(8)));
typedef __bf16 bf16x4 __attribute__((ext_vector_type(4)));
typedef float f32x4 __attribute__((ext_vector_type(4)));

#define GLOBAL_AS(p) ((const __attribute__((address_space(1))) void*)(p))
#define LDS_AS(p)    ((__attribute__((address_space(3))) void*)(p))

// load 8 f32 -> bf16x8, nontemporal when NT (read-once streams: keep L3 for H3)
template<int NT>
__device__ inline bf16x8 ldcvt8(const float* __restrict__ p) {
    f32x4 f0, f1;
    if constexpr (NT) {
        f0 = __builtin_nontemporal_load(reinterpret_cast<const f32x4*>(p));
        f1 = __builtin_nontemporal_load(reinterpret_cast<const f32x4*>(p) + 1);
    } else {
        f0 = reinterpret_cast<const f32x4*>(p)[0];
        f1 = reinterpret_cast<const f32x4*>(p)[1];
    }
    bf16x8 r;
    r[0] = (__bf16)f0[0]; r[1] = (__bf16)f0[1]; r[2] = (__bf16)f0[2]; r[3] = (__bf16)f0[3];
    r[4] = (__bf16)f1[0]; r[5] = (__bf16)f1[1]; r[6] = (__bf16)f1[2]; r[7] = (__bf16)f1[3];
    return r;
}

// ---------------------------------------------------------------------------
// Fused GEMM: OUT = epilogue(A @ B^T + bias), A:(nrow,KDIM), B:(256,KDIM) bf16.
// MODE 0: relu -> OUTB bf16, batched over blockIdx.y = relation (A/bias/B/out
//         selected per relation); A0 reads are nontemporal.
// MODE 1: relu + row L2-norm -> OUTF f32 (final); A = [A0 f32 | A1 bf16].
// Tile: BM=128 x BN=256, BK=32, 8 waves, dbuf LDS; B via global_load_lds w=16.
// ---------------------------------------------------------------------------
template<int KDIM, int MODE>
__global__ __launch_bounds__(512) void gemm_fused(
    const float* __restrict__ A0a, const float* __restrict__ A0b,
    const float* __restrict__ A0c, const __bf16* __restrict__ A1,
    const __bf16* __restrict__ Bmat, const float* __restrict__ ba,
    const float* __restrict__ bb, const float* __restrict__ bc,
    float* __restrict__ OUTF, __bf16* __restrict__ OUTB, int nrow)
{
    __shared__ __bf16 As[2][128 * 32];
    __shared__ __bf16 Bs[2][256 * 32];
    __shared__ float rs[4][128];

    const int rel = blockIdx.y;
    const float* A0 = (rel == 0) ? A0a : (rel == 1) ? A0b : A0c;
    const float* bias = (rel == 0) ? ba : (rel == 1) ? bb : bc;
    const __bf16* B = Bmat + (size_t)rel * 256 * KDIM;
    __bf16* OUTBr = (MODE == 0) ? OUTB + (size_t)rel * nrow * DIM : OUTB;

    const int tid = threadIdx.x;
    const int w = tid >> 6, lane = tid & 63;
    const int wr = w >> 2, wc = w & 3;
    const int lr = lane & 15, lk = (lane >> 4) << 3;
    const int r0 = blockIdx.x << 7;

    const int srow = tid >> 2;
    const int scb  = (tid & 3) << 3;
    const int arow_g = min(r0 + srow, nrow - 1);
    const int brow0 = (w << 4) + (lane >> 2);
    const int bcol  = (lane & 3) << 3;

    const int KT = KDIM / 32;
    f32x4 acc[4][4] = {};

    {
        bf16x8 av = ldcvt8<MODE == 0>(A0 + (size_t)arow_g * DIM + scb);
        *reinterpret_cast<bf16x8*>(&As[0][srow * 32 + scb]) = av;
        __builtin_amdgcn_global_load_lds(
            GLOBAL_AS(B + (size_t)brow0 * KDIM + bcol),
            LDS_AS(&Bs[0][(w << 4) * 32]), 16, 0, 0);
        __builtin_amdgcn_global_load_lds(
            GLOBAL_AS(B + (size_t)(brow0 + 128) * KDIM + bcol),
            LDS_AS(&Bs[0][(128 + (w << 4)) * 32]), 16, 0, 0);
    }
    __syncthreads();

    int buf = 0;
    for (int kt = 0; kt < KT; ++kt) {
        const bool has_next = (kt + 1 < KT);
        bf16x8 av;
        if (has_next) {
            const int kn = (kt + 1) << 5;
            __builtin_amdgcn_global_load_lds(
                GLOBAL_AS(B + (size_t)brow0 * KDIM + kn + bcol),
                LDS_AS(&Bs[buf ^ 1][(w << 4) * 32]), 16, 0, 0);
            __builtin_amdgcn_global_load_lds(
                GLOBAL_AS(B + (size_t)(brow0 + 128) * KDIM + kn + bcol),
                LDS_AS(&Bs[buf ^ 1][(128 + (w << 4)) * 32]), 16, 0, 0);
            if (KDIM == 512 && kn >= DIM) {
                av = *reinterpret_cast<const bf16x8*>(
                    A1 + (size_t)arow_g * DIM + (kn - DIM) + scb);
            } else {
                av = ldcvt8<MODE == 0>(A0 + (size_t)arow_g * DIM + kn + scb);
            }
        }

        bf16x8 afr[4], bfr[4];
#pragma unroll
        for (int mt = 0; mt < 4; ++mt)
            afr[mt] = *reinterpret_cast<const bf16x8*>(
                &As[buf][((wr << 6) + (mt << 4) + lr) * 32 + lk]);
#pragma unroll
        for (int nt = 0; nt < 4; ++nt)
            bfr[nt] = *reinterpret_cast<const bf16x8*>(
                &Bs[buf][((wc << 6) + (nt << 4) + lr) * 32 + lk]);
#pragma unroll
        for (int mt = 0; mt < 4; ++mt)
#pragma unroll
            for (int nt = 0; nt < 4; ++nt)
                acc[mt][nt] = __builtin_amdgcn_mfma_f32_16x16x32_bf16(
                    afr[mt], bfr[nt], acc[mt][nt], 0, 0, 0);

        if (has_next)
            *reinterpret_cast<bf16x8*>(&As[buf ^ 1][srow * 32 + scb]) = av;
        __syncthreads();
        buf ^= 1;
    }

    const int rbase = (lane >> 4) << 2;
    float bcolv[4];
#pragma unroll
    for (int nt = 0; nt < 4; ++nt) bcolv[nt] = bias[(wc << 6) + (nt << 4) + lr];

    if (MODE == 0) {
#pragma unroll
        for (int mt = 0; mt < 4; ++mt)
#pragma unroll
            for (int r = 0; r < 4; ++r) {
                int row = r0 + (wr << 6) + (mt << 4) + rbase + r;
                if (row >= nrow) continue;
#pragma unroll
                for (int nt = 0; nt < 4; ++nt) {
                    float v = fmaxf(acc[mt][nt][r] + bcolv[nt], 0.0f);
                    OUTBr[(size_t)row * DIM + (wc << 6) + (nt << 4) + lr] = (__bf16)v;
                }
            }
    } else {
        float ssq[4][4];
#pragma unroll
        for (int mt = 0; mt < 4; ++mt)
#pragma unroll
            for (int r = 0; r < 4; ++r) {
                float ss = 0.0f;
#pragma unroll
                for (int nt = 0; nt < 4; ++nt) {
                    float v = fmaxf(acc[mt][nt][r] + bcolv[nt], 0.0f);
                    acc[mt][nt][r] = v;
                    ss += v * v;
                }
                ss += __shfl_xor(ss, 1);
                ss += __shfl_xor(ss, 2);
                ss += __shfl_xor(ss, 4);
                ss += __shfl_xor(ss, 8);
                ssq[mt][r] = ss;
            }
        if (lr == 0) {
#pragma unroll
            for (int mt = 0; mt < 4; ++mt)
#pragma unroll
                for (int r = 0; r < 4; ++r)
                    rs[wc][(wr << 6) + (mt << 4) + rbase + r] = ssq[mt][r];
        }
        __syncthreads();
#pragma unroll
        for (int mt = 0; mt < 4; ++mt)
#pragma unroll
            for (int r = 0; r < 4; ++r) {
                int rl = (wr << 6) + (mt << 4) + rbase + r;
                int row = r0 + rl;
                if (row >= nrow) continue;
                float tot = rs[0][rl] + rs[1][rl] + rs[2][rl] + rs[3][rl];
                float invn = 1.0f / fmaxf(sqrtf(tot), 1e-12f);
#pragma unroll
                for (int nt = 0; nt < 4; ++nt)
                    __builtin_nontemporal_store(
                        acc[mt][nt][r] * invn,
                        &OUTF[(size_t)row * DIM + (wc << 6) + (nt << 4) + lr]);
            }
    }
}

// ---------------------------------------------------------------------------
// all weight conversions in one dispatch: WB[3*65536] then WLB[131072]
__global__ __launch_bounds__(256) void cvt_weights(
    const float* __restrict__ Wa, const float* __restrict__ Wp,
    const float* __restrict__ Wv, const float* __restrict__ Wl,
    __bf16* __restrict__ WB, __bf16* __restrict__ WLB)
{
    int i = blockIdx.x * 256 + threadIdx.x;
    if (i < 196608) {
        const float* src = (i < 65536) ? Wa : (i < 131072) ? Wp : Wv;
        int off = (i < 65536) ? i : (i < 131072) ? i - 65536 : i - 131072;
        WB[i] = (__bf16)src[off];
    } else if (i < 196608 + 131072) {
        int j = i - 196608;
        WLB[j] = (__bf16)Wl[j];
    }
}

__global__ __launch_bounds__(256) void hist3(
    const int* __restrict__ ea, const int* __restrict__ ep,
    const int* __restrict__ ev, int* __restrict__ cnt3, int E, int N)
{
    int e = blockIdx.x * 256 + threadIdx.x;
    if (e >= E) return;
    atomicAdd(&cnt3[ea[e]], 1);
    atomicAdd(&cnt3[N + ep[e]], 1);
    atomicAdd(&cnt3[2 * N + ev[e]], 1);
}

__global__ __launch_bounds__(256) void seg3(
    const int* __restrict__ cnt3, int* __restrict__ start3,
    int* __restrict__ cursor3, int* __restrict__ total, int n3)
{
    int i = blockIdx.x * 256 + threadIdx.x;
    int lane = threadIdx.x & 63;
    int c = (i < n3) ? cnt3[i] : 0;
    int p = c;
#pragma unroll
    for (int m = 1; m < 64; m <<= 1) {
        int t = __shfl_up(p, m);
        if (lane >= m) p += t;
    }
    int wsum = __shfl(p, 63);
    int base = 0;
    if (lane == 63) base = atomicAdd(total, wsum);
    base = __shfl(base, 63);
    if (i < n3) {
        int st = base + p - c;
        start3[i] = st;
        cursor3[i] = st;
    }
}

// arena entries packed as int2(tgt, bits(w))
__global__ __launch_bounds__(256) void fill3(
    const int* __restrict__ ea, const int* __restrict__ ep,
    const int* __restrict__ ev, const float* __restrict__ wa,
    const float* __restrict__ wp, const float* __restrict__ wv,
    int* __restrict__ cursor3, int2* __restrict__ edges, int E, int N)
{
    int e = blockIdx.x * 256 + threadIdx.x;
    if (e >= E) return;
    int s, pos;
    s = ea[e]; pos = atomicAdd(&cursor3[s], 1);
    edges[pos] = make_int2(ea[E + e], __float_as_int(wa[e]));
    s = ep[e]; pos = atomicAdd(&cursor3[N + s], 1);
    edges[pos] = make_int2(ep[E + e], __float_as_int(wp[e]));
    s = ev[e]; pos = atomicAdd(&cursor3[2 * N + s], 1);
    edges[pos] = make_int2(ev[E + e], __float_as_int(wv[e]));
}

// ---------------------------------------------------------------------------
// Per node (1 wave): 3-relation gather-mean + score + softmax-combine.
// Half-wave split: 2 edges in flight, 16B bf16x8 loads; edge metadata
// preloaded lane-parallel and broadcast via shfl (register-only).
// ---------------------------------------------------------------------------
__global__ __launch_bounds__(256) void gather3(
    const __bf16* __restrict__ H3, const int* __restrict__ start3,
    const int* __restrict__ cnt3, const int2* __restrict__ edges,
    const float* __restrict__ x_node, const float* __restrict__ u,
    __bf16* __restrict__ CB, int N)
{
    int i = (blockIdx.x << 2) + (threadIdx.x >> 6);
    if (i >= N) return;
    const int lane = threadIdx.x & 63;
    const int half = lane >> 5;
    const int l32 = lane & 31;

    // xu = dot(x_node[i], u2)  (full wave, 4 f32/lane)
    float4 u2 = *reinterpret_cast<const float4*>(u + DIM + (lane << 2));
    float4 xn = *reinterpret_cast<const float4*>(x_node + (size_t)i * DIM + (lane << 2));
    float xu = xn.x * u2.x + xn.y * u2.y + xn.z * u2.z + xn.w * u2.w;
#pragma unroll
    for (int m = 1; m < 64; m <<= 1) xu += __shfl_xor(xu, m);

    // u1 in half-layout: lane holds elems [l32*8, l32*8+8)
    float4 u1a = *reinterpret_cast<const float4*>(u + (l32 << 3));
    float4 u1b = *reinterpret_cast<const float4*>(u + (l32 << 3) + 4);

    float ags[3][8];
    float sc[3];
#pragma unroll 1
    for (int r = 0; r < 3; ++r) {
        const int base = r * N + i;
        const int s0 = start3[base];
        const int c = cnt3[base];
        const __bf16* __restrict__ H = H3 + (size_t)r * N * DIM;
        float a[8] = {0.f, 0.f, 0.f, 0.f, 0.f, 0.f, 0.f, 0.f};

        for (int ch = 0; ch < c; ch += 32) {
            const int nc = min(32, c - ch);
            int2 pr = make_int2(0, 0);
            if (half == 0 && l32 < nc) pr = edges[s0 + ch + l32];
            const int npairs = (nc + 1) >> 1;
            for (int j = 0; j < npairs; ++j) {
                const int e = (j << 1) + half;           // lanes >= nc hold (0,0)
                const int trow = __shfl(pr.x, e);
                const float wgt = __int_as_float(__shfl(pr.y, e));
                bf16x8 h = *reinterpret_cast<const bf16x8*>(
                    H + (size_t)trow * DIM + (l32 << 3));
#pragma unroll
                for (int k = 0; k < 8; ++k) a[k] += (float)h[k] * wgt;
            }
        }
#pragma unroll
        for (int k = 0; k < 8; ++k) a[k] += __shfl_xor(a[k], 32);
        const float inv = 1.0f / fmaxf((float)c, 1.0f);
#pragma unroll
        for (int k = 0; k < 8; ++k) { a[k] *= inv; ags[r][k] = a[k]; }
        float pa = a[0] * u1a.x + a[1] * u1a.y + a[2] * u1a.z + a[3] * u1a.w
                 + a[4] * u1b.x + a[5] * u1b.y + a[6] * u1b.z + a[7] * u1b.w;
#pragma unroll
        for (int m = 1; m < 32; m <<= 1) pa += __shfl_xor(pa, m);
        float z = pa + xu;
        sc[r] = expf((z > 0.0f) ? z : 0.01f * z);
    }

    const float invden = 1.0f / (sc[0] + sc[1] + sc[2]);
    if (half == 0) {
        bf16x8 ob;
#pragma unroll
        for (int k = 0; k < 8; ++k) {
            float o = (sc[0] * ags[0][k] + sc[1] * ags[1][k] + sc[2] * ags[2][k]) * invden;
            ob[k] = (__bf16)o;
        }
        *reinterpret_cast<bf16x8*>(CB + (size_t)i * DIM + (l32 << 3)) = ob;
    }
}

// ---------------------------------------------------------------------------
extern "C" void kernel_launch(void* const* d_in, const int* in_sizes, int n_in,
                              void* d_out, int out_size, void* d_ws, size_t ws_size,
                              hipStream_t stream)
{
    const float* x_a    = (const float*)d_in[0];
    const float* x_p    = (const float*)d_in[1];
    const float* x_v    = (const float*)d_in[2];
    const int*   edge_a = (const int*)d_in[3];
    const int*   edge_p = (const int*)d_in[4];
    const int*   edge_v = (const int*)d_in[5];
    const float* ew_a   = (const float*)d_in[6];
    const float* ew_p   = (const float*)d_in[7];
    const float* ew_v   = (const float*)d_in[8];
    const float* x_node = (const float*)d_in[9];
    const float* W_a    = (const float*)d_in[11];
    const float* b_a    = (const float*)d_in[12];
    const float* W_p    = (const float*)d_in[13];
    const float* b_p    = (const float*)d_in[14];
    const float* W_v    = (const float*)d_in[15];
    const float* b_v    = (const float*)d_in[16];
    const float* u      = (const float*)d_in[17];
    const float* W_lin  = (const float*)d_in[18];
    const float* b_lin  = (const float*)d_in[19];
    float* out = (float*)d_out;

    const int N = in_sizes[0] / DIM;
    const int E = in_sizes[6];

    __bf16* H3     = (__bf16*)d_ws;                     // 3*N*256
    __bf16* CB     = H3 + (size_t)3 * N * DIM;          // N*256
    __bf16* WB     = CB + (size_t)N * DIM;              // 3*65536
    __bf16* WLB    = WB + 3 * 65536;                    // 131072
    int2*   edges  = (int2*)(WLB + 131072);             // 3E
    int*    cnt3   = (int*)(edges + (size_t)3 * E);     // 3N
    int*    start3 = cnt3 + 3 * N;                      // 3N
    int*    cursor3= start3 + 3 * N;                    // 3N
    int*    total  = cursor3 + 3 * N;                   // 1

    const int gemm_grid = (N + 127) / 128;
    const int egrid = (E + 255) / 256;

    cvt_weights<<<1280, 256, 0, stream>>>(W_a, W_p, W_v, W_lin, WB, WLB);

    hipMemsetAsync(cnt3, 0, (size_t)3 * N * sizeof(int), stream);
    hipMemsetAsync(total, 0, sizeof(int), stream);
    hist3<<<egrid, 256, 0, stream>>>(edge_a, edge_p, edge_v, cnt3, E, N);
    seg3<<<(3 * N + 255) / 256, 256, 0, stream>>>(cnt3, start3, cursor3, total, 3 * N);
    fill3<<<egrid, 256, 0, stream>>>(edge_a, edge_p, edge_v, ew_a, ew_p, ew_v,
                                     cursor3, edges, E, N);

    // batched H_r = relu(X_r @ W_r^T + b_r)
    gemm_fused<256, 0><<<dim3(gemm_grid, 3), 512, 0, stream>>>(
        x_a, x_p, x_v, (const __bf16*)nullptr, WB, b_a, b_p, b_v,
        (float*)nullptr, H3, N);

    gather3<<<(N + 3) / 4, 256, 0, stream>>>(H3, start3, cnt3, edges,
                                             x_node, u, CB, N);

    gemm_fused<512, 1><<<dim3(gemm_grid, 1), 512, 0, stream>>>(
        x_node, x_node, x_node, CB, WLB, b_lin, b_lin, b_lin,
        out, (__bf16*)nullptr, N);
}

// Round 5
// 320.561 us; speedup vs baseline: 10.9416x; 1.0611x over previous
//
#include <hip/hip_runtime.h>
#include <math.h>

#define DIM 256

typedef __bf16 bf16x8 __attribute__((ext_vector_type(8)));
typedef __bf16 bf16x4 __attribute__((ext_vector_type(4)));
typedef float f32x4 __attribute__((ext_vector_type(4)));

#define GLOBAL_AS(p) ((const __attribute__((address_space(1))) void*)(p))
#define LDS_AS(p)    ((__attribute__((address_space(3))) void*)(p))

// load 8 f32 -> bf16x8, nontemporal when NT (read-once streams)
template<int NT>
__device__ inline bf16x8 ldcvt8(const float* __restrict__ p) {
    f32x4 f0, f1;
    if constexpr (NT) {
        f0 = __builtin_nontemporal_load(reinterpret_cast<const f32x4*>(p));
        f1 = __builtin_nontemporal_load(reinterpret_cast<const f32x4*>(p) + 1);
    } else {
        f0 = reinterpret_cast<const f32x4*>(p)[0];
        f1 = reinterpret_cast<const f32x4*>(p)[1];
    }
    bf16x8 r;
    r[0] = (__bf16)f0[0]; r[1] = (__bf16)f0[1]; r[2] = (__bf16)f0[2]; r[3] = (__bf16)f0[3];
    r[4] = (__bf16)f1[0]; r[5] = (__bf16)f1[1]; r[6] = (__bf16)f1[2]; r[7] = (__bf16)f1[3];
    return r;
}

// ---------------------------------------------------------------------------
// Fused GEMM: OUT = epilogue(A @ B^T + bias), A:(nrow,KDIM), B:(256,KDIM) bf16.
// MODE 0: relu -> OUTB bf16, batched over blockIdx.y = relation.
// MODE 1: relu + row L2-norm -> OUTF f32 (final); A = [A0 f32 | A1 bf16].
// Tile: BM=128 x BN=256, BK=32, 8 waves, dbuf LDS; B via global_load_lds w=16.
// ---------------------------------------------------------------------------
template<int KDIM, int MODE>
__global__ __launch_bounds__(512) void gemm_fused(
    const float* __restrict__ A0a, const float* __restrict__ A0b,
    const float* __restrict__ A0c, const __bf16* __restrict__ A1,
    const __bf16* __restrict__ Bmat, const float* __restrict__ ba,
    const float* __restrict__ bb, const float* __restrict__ bc,
    float* __restrict__ OUTF, __bf16* __restrict__ OUTB, int nrow)
{
    __shared__ __bf16 As[2][128 * 32];
    __shared__ __bf16 Bs[2][256 * 32];
    __shared__ float rs[4][128];

    const int rel = blockIdx.y;
    const float* A0 = (rel == 0) ? A0a : (rel == 1) ? A0b : A0c;
    const float* bias = (rel == 0) ? ba : (rel == 1) ? bb : bc;
    const __bf16* B = Bmat + (size_t)rel * 256 * KDIM;
    __bf16* OUTBr = (MODE == 0) ? OUTB + (size_t)rel * nrow * DIM : OUTB;

    const int tid = threadIdx.x;
    const int w = tid >> 6, lane = tid & 63;
    const int wr = w >> 2, wc = w & 3;
    const int lr = lane & 15, lk = (lane >> 4) << 3;
    const int r0 = blockIdx.x << 7;

    const int srow = tid >> 2;
    const int scb  = (tid & 3) << 3;
    const int arow_g = min(r0 + srow, nrow - 1);
    const int brow0 = (w << 4) + (lane >> 2);
    const int bcol  = (lane & 3) << 3;

    const int KT = KDIM / 32;
    f32x4 acc[4][4] = {};

    {
        bf16x8 av = ldcvt8<MODE == 0>(A0 + (size_t)arow_g * DIM + scb);
        *reinterpret_cast<bf16x8*>(&As[0][srow * 32 + scb]) = av;
        __builtin_amdgcn_global_load_lds(
            GLOBAL_AS(B + (size_t)brow0 * KDIM + bcol),
            LDS_AS(&Bs[0][(w << 4) * 32]), 16, 0, 0);
        __builtin_amdgcn_global_load_lds(
            GLOBAL_AS(B + (size_t)(brow0 + 128) * KDIM + bcol),
            LDS_AS(&Bs[0][(128 + (w << 4)) * 32]), 16, 0, 0);
    }
    __syncthreads();

    int buf = 0;
    for (int kt = 0; kt < KT; ++kt) {
        const bool has_next = (kt + 1 < KT);
        bf16x8 av;
        if (has_next) {
            const int kn = (kt + 1) << 5;
            __builtin_amdgcn_global_load_lds(
                GLOBAL_AS(B + (size_t)brow0 * KDIM + kn + bcol),
                LDS_AS(&Bs[buf ^ 1][(w << 4) * 32]), 16, 0, 0);
            __builtin_amdgcn_global_load_lds(
                GLOBAL_AS(B + (size_t)(brow0 + 128) * KDIM + kn + bcol),
                LDS_AS(&Bs[buf ^ 1][(128 + (w << 4)) * 32]), 16, 0, 0);
            if (KDIM == 512 && kn >= DIM) {
                av = *reinterpret_cast<const bf16x8*>(
                    A1 + (size_t)arow_g * DIM + (kn - DIM) + scb);
            } else {
                av = ldcvt8<MODE == 0>(A0 + (size_t)arow_g * DIM + kn + scb);
            }
        }

        bf16x8 afr[4], bfr[4];
#pragma unroll
        for (int mt = 0; mt < 4; ++mt)
            afr[mt] = *reinterpret_cast<const bf16x8*>(
                &As[buf][((wr << 6) + (mt << 4) + lr) * 32 + lk]);
#pragma unroll
        for (int nt = 0; nt < 4; ++nt)
            bfr[nt] = *reinterpret_cast<const bf16x8*>(
                &Bs[buf][((wc << 6) + (nt << 4) + lr) * 32 + lk]);
#pragma unroll
        for (int mt = 0; mt < 4; ++mt)
#pragma unroll
            for (int nt = 0; nt < 4; ++nt)
                acc[mt][nt] = __builtin_amdgcn_mfma_f32_16x16x32_bf16(
                    afr[mt], bfr[nt], acc[mt][nt], 0, 0, 0);

        if (has_next)
            *reinterpret_cast<bf16x8*>(&As[buf ^ 1][srow * 32 + scb]) = av;
        __syncthreads();
        buf ^= 1;
    }

    const int rbase = (lane >> 4) << 2;
    float bcolv[4];
#pragma unroll
    for (int nt = 0; nt < 4; ++nt) bcolv[nt] = bias[(wc << 6) + (nt << 4) + lr];

    if (MODE == 0) {
#pragma unroll
        for (int mt = 0; mt < 4; ++mt)
#pragma unroll
            for (int r = 0; r < 4; ++r) {
                int row = r0 + (wr << 6) + (mt << 4) + rbase + r;
                if (row >= nrow) continue;
#pragma unroll
                for (int nt = 0; nt < 4; ++nt) {
                    float v = fmaxf(acc[mt][nt][r] + bcolv[nt], 0.0f);
                    OUTBr[(size_t)row * DIM + (wc << 6) + (nt << 4) + lr] = (__bf16)v;
                }
            }
    } else {
        float ssq[4][4];
#pragma unroll
        for (int mt = 0; mt < 4; ++mt)
#pragma unroll
            for (int r = 0; r < 4; ++r) {
                float ss = 0.0f;
#pragma unroll
                for (int nt = 0; nt < 4; ++nt) {
                    float v = fmaxf(acc[mt][nt][r] + bcolv[nt], 0.0f);
                    acc[mt][nt][r] = v;
                    ss += v * v;
                }
                ss += __shfl_xor(ss, 1);
                ss += __shfl_xor(ss, 2);
                ss += __shfl_xor(ss, 4);
                ss += __shfl_xor(ss, 8);
                ssq[mt][r] = ss;
            }
        if (lr == 0) {
#pragma unroll
            for (int mt = 0; mt < 4; ++mt)
#pragma unroll
                for (int r = 0; r < 4; ++r)
                    rs[wc][(wr << 6) + (mt << 4) + rbase + r] = ssq[mt][r];
        }
        __syncthreads();
#pragma unroll
        for (int mt = 0; mt < 4; ++mt)
#pragma unroll
            for (int r = 0; r < 4; ++r) {
                int rl = (wr << 6) + (mt << 4) + rbase + r;
                int row = r0 + rl;
                if (row >= nrow) continue;
                float tot = rs[0][rl] + rs[1][rl] + rs[2][rl] + rs[3][rl];
                float invn = 1.0f / fmaxf(sqrtf(tot), 1e-12f);
#pragma unroll
                for (int nt = 0; nt < 4; ++nt)
                    __builtin_nontemporal_store(
                        acc[mt][nt][r] * invn,
                        &OUTF[(size_t)row * DIM + (wc << 6) + (nt << 4) + lr]);
            }
    }
}

// ---------------------------------------------------------------------------
__global__ __launch_bounds__(256) void cvt_weights(
    const float* __restrict__ Wa, const float* __restrict__ Wp,
    const float* __restrict__ Wv, const float* __restrict__ Wl,
    __bf16* __restrict__ WB, __bf16* __restrict__ WLB)
{
    int i = blockIdx.x * 256 + threadIdx.x;
    if (i < 196608) {
        const float* src = (i < 65536) ? Wa : (i < 131072) ? Wp : Wv;
        int off = (i < 65536) ? i : (i < 131072) ? i - 65536 : i - 131072;
        WB[i] = (__bf16)src[off];
    } else if (i < 196608 + 131072) {
        int j = i - 196608;
        WLB[j] = (__bf16)Wl[j];
    }
}

__global__ __launch_bounds__(256) void hist3(
    const int* __restrict__ ea, const int* __restrict__ ep,
    const int* __restrict__ ev, int* __restrict__ cnt3, int E, int N)
{
    int e = blockIdx.x * 256 + threadIdx.x;
    if (e >= E) return;
    atomicAdd(&cnt3[ea[e]], 1);
    atomicAdd(&cnt3[N + ep[e]], 1);
    atomicAdd(&cnt3[2 * N + ev[e]], 1);
}

__global__ __launch_bounds__(256) void seg3(
    const int* __restrict__ cnt3, int* __restrict__ start3,
    int* __restrict__ cursor3, int* __restrict__ total, int n3)
{
    int i = blockIdx.x * 256 + threadIdx.x;
    int lane = threadIdx.x & 63;
    int c = (i < n3) ? cnt3[i] : 0;
    int p = c;
#pragma unroll
    for (int m = 1; m < 64; m <<= 1) {
        int t = __shfl_up(p, m);
        if (lane >= m) p += t;
    }
    int wsum = __shfl(p, 63);
    int base = 0;
    if (lane == 63) base = atomicAdd(total, wsum);
    base = __shfl(base, 63);
    if (i < n3) {
        int st = base + p - c;
        start3[i] = st;
        cursor3[i] = st;
    }
}

// arena entries packed as int2(tgt, bits(w))
__global__ __launch_bounds__(256) void fill3(
    const int* __restrict__ ea, const int* __restrict__ ep,
    const int* __restrict__ ev, const float* __restrict__ wa,
    const float* __restrict__ wp, const float* __restrict__ wv,
    int* __restrict__ cursor3, int2* __restrict__ edges, int E, int N)
{
    int e = blockIdx.x * 256 + threadIdx.x;
    if (e >= E) return;
    int s, pos;
    s = ea[e]; pos = atomicAdd(&cursor3[s], 1);
    edges[pos] = make_int2(ea[E + e], __float_as_int(wa[e]));
    s = ep[e]; pos = atomicAdd(&cursor3[N + s], 1);
    edges[pos] = make_int2(ep[E + e], __float_as_int(wp[e]));
    s = ev[e]; pos = atomicAdd(&cursor3[2 * N + s], 1);
    edges[pos] = make_int2(ev[E + e], __float_as_int(wv[e]));
}

// ---------------------------------------------------------------------------
// Per node (1 wave): 3-relation gather-mean + score + softmax-combine.
// All three relations interleaved in one j-loop -> 6 independent H-row loads
// in flight (2 edges x 3 relations). Zero-padded edge regs keep the loop
// uniform: exhausted slots load row 0 with weight 0 (cache-hot, harmless).
// ---------------------------------------------------------------------------
__global__ __launch_bounds__(256) void gather3(
    const __bf16* __restrict__ H3, const int* __restrict__ start3,
    const int* __restrict__ cnt3, const int2* __restrict__ edges,
    const float* __restrict__ x_node, const float* __restrict__ u,
    __bf16* __restrict__ CB, int N)
{
    int i = (blockIdx.x << 2) + (threadIdx.x >> 6);
    if (i >= N) return;
    const int lane = threadIdx.x & 63;
    const int half = lane >> 5;
    const int l32 = lane & 31;

    // hoist all metadata (independent loads)
    const int s00 = start3[i],         c0 = cnt3[i];
    const int s01 = start3[N + i],     c1 = cnt3[N + i];
    const int s02 = start3[2 * N + i], c2 = cnt3[2 * N + i];
    const __bf16* __restrict__ H0 = H3;
    const __bf16* __restrict__ H1 = H3 + (size_t)N * DIM;
    const __bf16* __restrict__ H2 = H3 + (size_t)2 * N * DIM;

    // xu = dot(x_node[i], u2)  (full wave, 4 f32/lane)
    float4 u2 = *reinterpret_cast<const float4*>(u + DIM + (lane << 2));
    float4 xn = *reinterpret_cast<const float4*>(x_node + (size_t)i * DIM + (lane << 2));
    float xu = xn.x * u2.x + xn.y * u2.y + xn.z * u2.z + xn.w * u2.w;
#pragma unroll
    for (int m = 1; m < 64; m <<= 1) xu += __shfl_xor(xu, m);

    // u1 in half-layout: lane holds elems [l32*8, l32*8+8)
    float4 u1a = *reinterpret_cast<const float4*>(u + (l32 << 3));
    float4 u1b = *reinterpret_cast<const float4*>(u + (l32 << 3) + 4);

    float a0[8] = {}, a1[8] = {}, a2[8] = {};
    const int cmax = max(max(c0, c1), c2);

    for (int ch = 0; ch < cmax; ch += 32) {
        int2 p0 = make_int2(0, 0), p1 = make_int2(0, 0), p2 = make_int2(0, 0);
        if (half == 0) {
            if (l32 < c0 - ch) p0 = edges[s00 + ch + l32];
            if (l32 < c1 - ch) p1 = edges[s01 + ch + l32];
            if (l32 < c2 - ch) p2 = edges[s02 + ch + l32];
        }
        const int jmax = (min(32, cmax - ch) + 1) >> 1;
        for (int j = 0; j < jmax; ++j) {
            const int e = (j << 1) + half;
            const int   t0 = __shfl(p0.x, e);
            const float w0 = __int_as_float(__shfl(p0.y, e));
            const int   t1 = __shfl(p1.x, e);
            const float w1 = __int_as_float(__shfl(p1.y, e));
            const int   t2 = __shfl(p2.x, e);
            const float w2 = __int_as_float(__shfl(p2.y, e));
            bf16x8 h0 = *reinterpret_cast<const bf16x8*>(H0 + (size_t)t0 * DIM + (l32 << 3));
            bf16x8 h1 = *reinterpret_cast<const bf16x8*>(H1 + (size_t)t1 * DIM + (l32 << 3));
            bf16x8 h2 = *reinterpret_cast<const bf16x8*>(H2 + (size_t)t2 * DIM + (l32 << 3));
#pragma unroll
            for (int k = 0; k < 8; ++k) a0[k] += (float)h0[k] * w0;
#pragma unroll
            for (int k = 0; k < 8; ++k) a1[k] += (float)h1[k] * w1;
#pragma unroll
            for (int k = 0; k < 8; ++k) a2[k] += (float)h2[k] * w2;
        }
    }

    // combine halves (each half accumulated different edges)
#pragma unroll
    for (int k = 0; k < 8; ++k) a0[k] += __shfl_xor(a0[k], 32);
#pragma unroll
    for (int k = 0; k < 8; ++k) a1[k] += __shfl_xor(a1[k], 32);
#pragma unroll
    for (int k = 0; k < 8; ++k) a2[k] += __shfl_xor(a2[k], 32);

    const float i0 = 1.0f / fmaxf((float)c0, 1.0f);
    const float i1 = 1.0f / fmaxf((float)c1, 1.0f);
    const float i2 = 1.0f / fmaxf((float)c2, 1.0f);
#pragma unroll
    for (int k = 0; k < 8; ++k) { a0[k] *= i0; a1[k] *= i1; a2[k] *= i2; }

    float pa0 = a0[0] * u1a.x + a0[1] * u1a.y + a0[2] * u1a.z + a0[3] * u1a.w
              + a0[4] * u1b.x + a0[5] * u1b.y + a0[6] * u1b.z + a0[7] * u1b.w;
    float pa1 = a1[0] * u1a.x + a1[1] * u1a.y + a1[2] * u1a.z + a1[3] * u1a.w
              + a1[4] * u1b.x + a1[5] * u1b.y + a1[6] * u1b.z + a1[7] * u1b.w;
    float pa2 = a2[0] * u1a.x + a2[1] * u1a.y + a2[2] * u1a.z + a2[3] * u1a.w
              + a2[4] * u1b.x + a2[5] * u1b.y + a2[6] * u1b.z + a2[7] * u1b.w;
#pragma unroll
    for (int m = 1; m < 32; m <<= 1) {
        pa0 += __shfl_xor(pa0, m);
        pa1 += __shfl_xor(pa1, m);
        pa2 += __shfl_xor(pa2, m);
    }

    float z0 = pa0 + xu, z1 = pa1 + xu, z2 = pa2 + xu;
    const float s0 = expf((z0 > 0.0f) ? z0 : 0.01f * z0);
    const float s1 = expf((z1 > 0.0f) ? z1 : 0.01f * z1);
    const float s2 = expf((z2 > 0.0f) ? z2 : 0.01f * z2);
    const float invden = 1.0f / (s0 + s1 + s2);

    if (half == 0) {
        bf16x8 ob;
#pragma unroll
        for (int k = 0; k < 8; ++k) {
            float o = (s0 * a0[k] + s1 * a1[k] + s2 * a2[k]) * invden;
            ob[k] = (__bf16)o;
        }
        *reinterpret_cast<bf16x8*>(CB + (size_t)i * DIM + (l32 << 3)) = ob;
    }
}

// ---------------------------------------------------------------------------
extern "C" void kernel_launch(void* const* d_in, const int* in_sizes, int n_in,
                              void* d_out, int out_size, void* d_ws, size_t ws_size,
                              hipStream_t stream)
{
    const float* x_a    = (const float*)d_in[0];
    const float* x_p    = (const float*)d_in[1];
    const float* x_v    = (const float*)d_in[2];
    const int*   edge_a = (const int*)d_in[3];
    const int*   edge_p = (const int*)d_in[4];
    const int*   edge_v = (const int*)d_in[5];
    const float* ew_a   = (const float*)d_in[6];
    const float* ew_p   = (const float*)d_in[7];
    const float* ew_v   = (const float*)d_in[8];
    const float* x_node = (const float*)d_in[9];
    const float* W_a    = (const float*)d_in[11];
    const float* b_a    = (const float*)d_in[12];
    const float* W_p    = (const float*)d_in[13];
    const float* b_p    = (const float*)d_in[14];
    const float* W_v    = (const float*)d_in[15];
    const float* b_v    = (const float*)d_in[16];
    const float* u      = (const float*)d_in[17];
    const float* W_lin  = (const float*)d_in[18];
    const float* b_lin  = (const float*)d_in[19];
    float* out = (float*)d_out;

    const int N = in_sizes[0] / DIM;
    const int E = in_sizes[6];

    __bf16* H3     = (__bf16*)d_ws;                     // 3*N*256
    __bf16* CB     = H3 + (size_t)3 * N * DIM;          // N*256
    __bf16* WB     = CB + (size_t)N * DIM;              // 3*65536
    __bf16* WLB    = WB + 3 * 65536;                    // 131072
    int2*   edges  = (int2*)(WLB + 131072);             // 3E
    int*    cnt3   = (int*)(edges + (size_t)3 * E);     // 3N
    int*    start3 = cnt3 + 3 * N;                      // 3N
    int*    cursor3= start3 + 3 * N;                    // 3N
    int*    total  = cursor3 + 3 * N;                   // 1

    const int gemm_grid = (N + 127) / 128;
    const int egrid = (E + 255) / 256;

    cvt_weights<<<1280, 256, 0, stream>>>(W_a, W_p, W_v, W_lin, WB, WLB);

    hipMemsetAsync(cnt3, 0, (size_t)3 * N * sizeof(int), stream);
    hipMemsetAsync(total, 0, sizeof(int), stream);
    hist3<<<egrid, 256, 0, stream>>>(edge_a, edge_p, edge_v, cnt3, E, N);
    seg3<<<(3 * N + 255) / 256, 256, 0, stream>>>(cnt3, start3, cursor3, total, 3 * N);
    fill3<<<egrid, 256, 0, stream>>>(edge_a, edge_p, edge_v, ew_a, ew_p, ew_v,
                                     cursor3, edges, E, N);

    // batched H_r = relu(X_r @ W_r^T + b_r)
    gemm_fused<256, 0><<<dim3(gemm_grid, 3), 512, 0, stream>>>(
        x_a, x_p, x_v, (const __bf16*)nullptr, WB, b_a, b_p, b_v,
        (float*)nullptr, H3, N);

    gather3<<<(N + 3) / 4, 256, 0, stream>>>(H3, start3, cnt3, edges,
                                             x_node, u, CB, N);

    gemm_fused<512, 1><<<dim3(gemm_grid, 1), 512, 0, stream>>>(
        x_node, x_node, x_node, CB, WLB, b_lin, b_lin, b_lin,
        out, (__bf16*)nullptr, N);
}